// Round 3
// 10560.643 us; speedup vs baseline: 1.0069x; 1.0069x over previous
//
#include <hip/hip_runtime.h>
#include <hip/hip_bf16.h>

#define NN 2048
#define HH 1024
#define MM 4096          // 4*H
#define NWG 128
#define TPB 256
#define SLOTS 8          // staged child h-rows per batch (max children/node = 8)

__device__ __forceinline__ float sigmoidf_(float x) {
    return 1.0f / (1.0f + __expf(-x));
}
// fp32 -> bf16 bits (RNE), finite inputs
__device__ __forceinline__ unsigned f2bf_bits(float f) {
    unsigned u = __float_as_uint(f);
    u += 0x7fffu + ((u >> 16) & 1u);
    return u >> 16;
}
__device__ __forceinline__ float bf_bits2f(unsigned s) {
    return __uint_as_float(s << 16);
}

// ---------------------------------------------------------------- init flags
__global__ void init_flags(int* flags) {
    if (threadIdx.x < NWG) flags[threadIdx.x] = -1;
}

// ---------------------------------------------------------------- scheduler
// level[t] = 0 if no children, else 1+max(level of children); children of t
// are j in [t-8, t-1] with par[j]==t. Counting-sort nodes by level (stable:
// ascending node id within a level -> reference accumulation order kept).
__global__ void build_sched(const int* __restrict__ parent_g,
                            int* __restrict__ order,   // [NN] nodes by level
                            int* __restrict__ off,     // [nlv+1] level offsets
                            int* __restrict__ nlv_g)
{
    __shared__ int par[NN];
    __shared__ int lvl[NN];
    __shared__ int cnt[NN + 1];
    const int tid = threadIdx.x;
    for (int i = tid; i < NN; i += TPB) par[i] = parent_g[i];
    for (int i = tid; i <= NN; i += TPB) cnt[i] = 0;
    __syncthreads();
    if (tid == 0) {
        int lm1 = 0, lm2 = 0, lm3 = 0, lm4 = 0, lm5 = 0, lm6 = 0, lm7 = 0, lm8 = 0;
        int maxl = 0;
        for (int t = 0; t < NN; ++t) {
            int l = -1;
            if (t >= 1 && par[t - 1] == t && lm1 > l) l = lm1;
            if (t >= 2 && par[t - 2] == t && lm2 > l) l = lm2;
            if (t >= 3 && par[t - 3] == t && lm3 > l) l = lm3;
            if (t >= 4 && par[t - 4] == t && lm4 > l) l = lm4;
            if (t >= 5 && par[t - 5] == t && lm5 > l) l = lm5;
            if (t >= 6 && par[t - 6] == t && lm6 > l) l = lm6;
            if (t >= 7 && par[t - 7] == t && lm7 > l) l = lm7;
            if (t >= 8 && par[t - 8] == t && lm8 > l) l = lm8;
            ++l;
            lvl[t] = l;
            cnt[l]++;
            if (l > maxl) maxl = l;
            lm8 = lm7; lm7 = lm6; lm6 = lm5; lm5 = lm4;
            lm4 = lm3; lm3 = lm2; lm2 = lm1; lm1 = l;
        }
        int run = 0;
        for (int l = 0; l <= maxl; ++l) {
            const int c = cnt[l];
            cnt[l] = run;
            off[l] = run;
            run += c;
        }
        off[maxl + 1] = run;       // == NN
        *nlv_g = maxl + 1;
        for (int t = 0; t < NN; ++t)
            order[cnt[lvl[t]]++] = t;   // stable: ascending node id per level
    }
}

// ---------------------------------------------------------------- gx GEMM
// gx[n][m] = sum_d emb[inputs[n]][d] * Wx[m][d] + bx[m]   (m = g*1024+h)
// Stored as bf16 bits (16 MB workspace); error ~1e-4 << 3.8e-3 threshold.
__global__ void __launch_bounds__(256) gx_gemm(
    const int* __restrict__ idx, const float* __restrict__ emb,
    const float* __restrict__ Wx, const float* __restrict__ bx,
    unsigned short* __restrict__ gx)
{
    __shared__ float As[16][64];
    __shared__ float Bs[16][64];
    const int tid = threadIdx.x;
    const int tx = tid & 15, ty = tid >> 4;
    const int mt = blockIdx.x, nt = blockIdx.y;
    const int lrow = tid >> 2;            // 0..63
    const int lk   = (tid & 3) << 2;      // 0,4,8,12
    const int gn = nt * 64 + lrow;
    const int gm = mt * 64 + lrow;
    const float* arow = emb + (size_t)idx[gn] * HH;
    const float* wrow = Wx + (size_t)gm * HH;
    float acc[4][4] = {};
    for (int k0 = 0; k0 < HH; k0 += 16) {
        float4 av = *(const float4*)(arow + k0 + lk);
        float4 wv = *(const float4*)(wrow + k0 + lk);
        __syncthreads();
        As[lk + 0][lrow] = av.x; As[lk + 1][lrow] = av.y;
        As[lk + 2][lrow] = av.z; As[lk + 3][lrow] = av.w;
        Bs[lk + 0][lrow] = wv.x; Bs[lk + 1][lrow] = wv.y;
        Bs[lk + 2][lrow] = wv.z; Bs[lk + 3][lrow] = wv.w;
        __syncthreads();
        #pragma unroll
        for (int k = 0; k < 16; ++k) {
            const float4 a = *(const float4*)&As[k][ty * 4];
            const float4 b = *(const float4*)&Bs[k][tx * 4];
            const float aa[4] = {a.x, a.y, a.z, a.w};
            const float bb[4] = {b.x, b.y, b.z, b.w};
            #pragma unroll
            for (int i = 0; i < 4; ++i)
                #pragma unroll
                for (int j = 0; j < 4; ++j)
                    acc[i][j] += aa[i] * bb[j];
        }
    }
    #pragma unroll
    for (int i = 0; i < 4; ++i) {
        const int gr = nt * 64 + ty * 4 + i;
        #pragma unroll
        for (int j = 0; j < 4; ++j) {
            const int gc = mt * 64 + tx * 4 + j;
            gx[(size_t)gr * MM + gc] = (unsigned short)f2bf_bits(acc[i][j] + bx[gc]);
        }
    }
}

// ---------------------------------------------------------------- tree scan
// Level-parallel schedule: one cross-WG flag barrier per LEVEL (~480) instead
// of per node (2048). Child h-rows of a level batch-staged into LDS in one
// pipelined pass. Level 0 (leaves) is fully elementwise-parallel.
// c state: 64 KB dynamic LDS (c_all[NN][8]) owned by the WG.
// R2 bug fixed here: the leaf fast-path dropped the bh biases (reference:
// i = sigmoid(gx + Wh@0 + bh) -- bh remains for leaves). bh staged per-WG
// into bh_s[4][8] and added in the leaf path.
__global__ void __launch_bounds__(TPB, 1) lstm_scan(
    const int* __restrict__ parent_g,
    const float* __restrict__ Wh,
    const float* __restrict__ bh,
    const unsigned short* __restrict__ gx,   // bf16 bits [N][4][H]
    const int* __restrict__ order_g,
    const int* __restrict__ off_g,
    const int* __restrict__ nlv_g,
    int* flags,
    float* out)   // fp32: [ hs (NN*HH) | c_root (HH) | h_root (HH) ]
{
    extern __shared__ float c_all[];   // [NN][8] = 64 KB dynamic LDS

    const int b      = blockIdx.x;
    const int tid    = threadIdx.x;
    const int e_loc  = tid >> 5;       // 0..7
    const int lane32 = tid & 31;
    const int e_glob = b * 8 + e_loc;

    __shared__ int   par[NN];            // 8 KB
    __shared__ int   order_s[NN];        // 8 KB
    __shared__ int   off_s[NN + 1];      // 8 KB
    __shared__ float stage[SLOTS][HH];   // 32 KB child h-rows
    __shared__ float gx_st[SLOTS][4][8]; // 1 KB
    __shared__ float bh_s[4][8];         // 128 B: bh[g][b*8+e] for owned elems
    __shared__ int   slot_j[SLOTS];      // child node id per stage slot

    for (int i = tid; i < NN; i += TPB) par[i] = parent_g[i];
    for (int i = tid; i < NN; i += TPB) order_s[i] = order_g[i];
    const int nlv = *nlv_g;
    for (int i = tid; i <= nlv; i += TPB) off_s[i] = off_g[i];
    if (tid < 32)
        bh_s[tid >> 3][tid & 7] = bh[(size_t)(tid >> 3) * HH + b * 8 + (tid & 7)];

    float w_i[32], w_o[32], w_u[32], w_f[32];
    {
        const float* wi = Wh + ((size_t)(0 * HH + e_glob)) * HH + lane32;
        const float* wo = Wh + ((size_t)(1 * HH + e_glob)) * HH + lane32;
        const float* wu = Wh + ((size_t)(2 * HH + e_glob)) * HH + lane32;
        const float* wf = Wh + ((size_t)(3 * HH + e_glob)) * HH + lane32;
        #pragma unroll
        for (int s = 0; s < 32; ++s) {
            w_i[s] = wi[s * 32];
            w_o[s] = wo[s * 32];
            w_u[s] = wu[s * 32];
            w_f[s] = wf[s * 32];
        }
    }
    const float bhi = bh[0 * HH + e_glob];
    const float bho = bh[1 * HH + e_glob];
    const float bhu = bh[2 * HH + e_glob];
    const float bhf = bh[3 * HH + e_glob];
    __syncthreads();

    int seen = -1;   // cached monotone lower bound of flags[tid] (tid < NWG)

    // ---- round 0: all leaves, elementwise-parallel, no cross-WG data
    {
        const int n0 = off_s[1];
        for (int base = 0; base < n0; base += 32) {
            const int i = base + (tid >> 3);
            if (i < n0) {
                const int t = order_s[i];
                const int e = tid & 7;
                const size_t g0 = (size_t)t * MM + b * 8 + e;
                const float iv = sigmoidf_(bf_bits2f(gx[g0]) + bh_s[0][e]);
                const float ov = sigmoidf_(bf_bits2f(gx[g0 + HH]) + bh_s[1][e]);
                const float uv = tanhf(bf_bits2f(gx[g0 + 2 * HH]) + bh_s[2][e]);
                const float c  = iv * uv;
                const float h  = ov * tanhf(c);
                c_all[t * 8 + e] = c;
                __hip_atomic_store(out + (size_t)t * HH + b * 8 + e, h,
                                   __ATOMIC_RELAXED, __HIP_MEMORY_SCOPE_AGENT);
            }
        }
        __syncthreads();   // drains vmcnt -> stores globally visible; c_all visible
        if (tid == 0)
            __hip_atomic_store(&flags[b], 0, __ATOMIC_RELEASE,
                               __HIP_MEMORY_SCOPE_AGENT);
    }

    // ---- rounds 1..nlv-1
    for (int r = 1; r < nlv; ++r) {
        // wait for ALL WGs to have published round r-1
        if (tid < NWG && seen < r - 1) {
            int v;
            while ((v = __hip_atomic_load(&flags[tid], __ATOMIC_ACQUIRE,
                                          __HIP_MEMORY_SCOPE_AGENT)) < r - 1)
                __builtin_amdgcn_s_sleep(1);
            seen = v;
        }
        __syncthreads();

        const int rend = off_s[r + 1];
        int idx = off_s[r];
        while (idx < rend) {
            // -- batch extent (uniform): take nodes until SLOTS children used
            int idx_end = idx, ns_tot = 0;
            while (idx_end < rend) {
                const int t  = order_s[idx_end];
                const int lo = t >= 8 ? t - 8 : 0;
                int k = 0;
                for (int j = lo; j < t; ++j) k += (par[j] == t);
                if (ns_tot + k > SLOTS) break;
                if (tid == 0) {
                    int s2 = ns_tot;
                    for (int j = lo; j < t; ++j)
                        if (par[j] == t) slot_j[s2++] = j;
                }
                ns_tot += k;
                ++idx_end;
            }
            const int nb = idx_end - idx;
            __syncthreads();   // slot_j visible

            // -- stage: all child h-rows flat (loads fully pipelined) + gx
            for (int w = tid; w < ns_tot * HH; w += TPB) {
                const int sl = w >> 10, k = w & (HH - 1);
                stage[sl][k] = __hip_atomic_load(
                    out + (size_t)slot_j[sl] * HH + k,
                    __ATOMIC_RELAXED, __HIP_MEMORY_SCOPE_AGENT);
            }
            if (tid < nb * 32) {
                const int bi = tid >> 5, g = (tid >> 3) & 3, e = tid & 7;
                const int t = order_s[idx + bi];
                gx_st[bi][g][e] =
                    bf_bits2f(gx[(size_t)t * MM + g * HH + b * 8 + e]);
            }
            __syncthreads();

            // -- compute: nodes sequential, no barriers (stage is read-only;
            //    c_all writes are to this level's nodes, reads from lower levels)
            int slot = 0;
            for (int ii = idx; ii < idx_end; ++ii) {
                const int bi = ii - idx;
                const int t  = order_s[ii];
                float hsum[32];
                #pragma unroll
                for (int s = 0; s < 32; ++s) hsum[s] = 0.0f;
                float fc = 0.0f;
                const int lo = t >= 8 ? t - 8 : 0;
                for (int j = lo; j < t; ++j) {
                    if (par[j] != t) continue;
                    float fdot = 0.0f;
                    #pragma unroll
                    for (int s = 0; s < 32; ++s) {
                        const float hv = stage[slot][lane32 + 32 * s];
                        hsum[s] += hv;
                        fdot += w_f[s] * hv;
                    }
                    #pragma unroll
                    for (int o2 = 16; o2 > 0; o2 >>= 1)
                        fdot += __shfl_down(fdot, o2, 32);
                    if (lane32 == 0)
                        fc += sigmoidf_(gx_st[bi][3][e_loc] + fdot + bhf)
                              * c_all[slot_j[slot] * 8 + e_loc];
                    ++slot;
                }
                float di = 0.0f, dv = 0.0f, du = 0.0f;
                #pragma unroll
                for (int s = 0; s < 32; ++s) {
                    di += w_i[s] * hsum[s];
                    dv += w_o[s] * hsum[s];
                    du += w_u[s] * hsum[s];
                }
                #pragma unroll
                for (int o2 = 16; o2 > 0; o2 >>= 1) {
                    di += __shfl_down(di, o2, 32);
                    dv += __shfl_down(dv, o2, 32);
                    du += __shfl_down(du, o2, 32);
                }
                if (lane32 == 0) {
                    const float iv = sigmoidf_(gx_st[bi][0][e_loc] + di + bhi);
                    const float ov = sigmoidf_(gx_st[bi][1][e_loc] + dv + bho);
                    const float uv = tanhf(gx_st[bi][2][e_loc] + du + bhu);
                    const float c  = iv * uv + fc;
                    const float h  = ov * tanhf(c);
                    c_all[t * 8 + e_loc] = c;
                    __hip_atomic_store(out + (size_t)t * HH + e_glob, h,
                                       __ATOMIC_RELAXED, __HIP_MEMORY_SCOPE_AGENT);
                    if (t == NN - 1) {
                        __hip_atomic_store(out + (size_t)NN * HH + e_glob, c,
                                           __ATOMIC_RELAXED, __HIP_MEMORY_SCOPE_AGENT);
                        __hip_atomic_store(out + (size_t)NN * HH + HH + e_glob, h,
                                           __ATOMIC_RELAXED, __HIP_MEMORY_SCOPE_AGENT);
                    }
                }
            }
            __syncthreads();   // stage/c_all reuse guard + drains compute stores
            idx = idx_end;
        }
        if (tid == 0)
            __hip_atomic_store(&flags[b], r, __ATOMIC_RELEASE,
                               __HIP_MEMORY_SCOPE_AGENT);
    }
}

// ---------------------------------------------------------------- launch
extern "C" void kernel_launch(void* const* d_in, const int* in_sizes, int n_in,
                              void* d_out, int out_size, void* d_ws, size_t ws_size,
                              hipStream_t stream)
{
    const int*   inputs = (const int*)d_in[0];
    const int*   parent = (const int*)d_in[1];
    const float* emb    = (const float*)d_in[2];
    const float* bx     = (const float*)d_in[4];
    const float* Wx     = (const float*)d_in[3];
    const float* Wh     = (const float*)d_in[5];
    const float* bh     = (const float*)d_in[6];
    float* out = (float*)d_out;          // fp32 output (reference is fp32)

    char* ws = (char*)d_ws;
    int*  flags = (int*)ws;                                     // 512 B
    unsigned short* gx = (unsigned short*)(ws + 1024);          // 16 MB bf16
    char* ws2 = ws + 1024 + (size_t)NN * MM * 2;
    int*  order = (int*)ws2;                                    // 8 KB
    int*  off   = (int*)(ws2 + 8192);                           // 8.2 KB
    int*  nlv   = (int*)(ws2 + 8192 + 8448);                    // 4 B

    // Opt in to >64 KB LDS (static ~57 KB + dynamic 64 KB = ~121 KB <= 160 KB)
    hipFuncSetAttribute(reinterpret_cast<const void*>(lstm_scan),
                        hipFuncAttributeMaxDynamicSharedMemorySize, 65536);

    hipLaunchKernelGGL(init_flags, dim3(1), dim3(128), 0, stream, flags);
    hipLaunchKernelGGL(build_sched, dim3(1), dim3(TPB), 0, stream,
                       parent, order, off, nlv);
    hipLaunchKernelGGL(gx_gemm, dim3(MM / 64, NN / 64), dim3(256), 0, stream,
                       inputs, emb, Wx, bx, gx);
    hipLaunchKernelGGL(lstm_scan, dim3(NWG), dim3(TPB), 65536, stream,
                       parent, Wh, bh, gx, order, off, nlv, flags, out);
}

// Round 4
// 7545.045 us; speedup vs baseline: 1.4093x; 1.3997x over previous
//
#include <hip/hip_runtime.h>
#include <hip/hip_bf16.h>

#define NN 2048
#define HH 1024
#define MM 4096          // 4*H
#define NWG 128
#define TPB 256
#define MAXC 12          // max staged child rows per batch
#define MAXNB 12         // max nodes per batch

__device__ __forceinline__ float sigmoidf_(float x) {
    return 1.0f / (1.0f + __expf(-x));
}
// fp32 -> bf16 bits (RNE), finite inputs
__device__ __forceinline__ unsigned f2bf_bits(float f) {
    unsigned u = __float_as_uint(f);
    u += 0x7fffu + ((u >> 16) & 1u);
    return u >> 16;
}
__device__ __forceinline__ float bf_bits2f(unsigned s) {
    return __uint_as_float(s << 16);
}

// ---------------------------------------------------------------- init flags
__global__ void init_flags(int* flags) {
    if (threadIdx.x < NWG) flags[threadIdx.x] = -1;
}

// ---------------------------------------------------------------- scheduler
// level[t] = 0 if no children, else 1+max(level of children); children of t
// are j in [t-8, t-1] with par[j]==t. Counting-sort nodes by level (stable:
// ascending node id within a level). Also emits lvl[] (needed by the scan to
// classify children as fresh (level r-1, tight wait) vs old (no wait)).
__global__ void build_sched(const int* __restrict__ parent_g,
                            int* __restrict__ order,   // [NN] nodes by level
                            int* __restrict__ off,     // [nlv+1] level offsets
                            int* __restrict__ nlv_g,
                            int* __restrict__ lvl_out) // [NN]
{
    __shared__ int par[NN];
    __shared__ int lvl[NN];
    __shared__ int cnt[NN + 1];
    const int tid = threadIdx.x;
    for (int i = tid; i < NN; i += TPB) par[i] = parent_g[i];
    for (int i = tid; i <= NN; i += TPB) cnt[i] = 0;
    __syncthreads();
    if (tid == 0) {
        int lm1 = 0, lm2 = 0, lm3 = 0, lm4 = 0, lm5 = 0, lm6 = 0, lm7 = 0, lm8 = 0;
        int maxl = 0;
        for (int t = 0; t < NN; ++t) {
            int l = -1;
            if (t >= 1 && par[t - 1] == t && lm1 > l) l = lm1;
            if (t >= 2 && par[t - 2] == t && lm2 > l) l = lm2;
            if (t >= 3 && par[t - 3] == t && lm3 > l) l = lm3;
            if (t >= 4 && par[t - 4] == t && lm4 > l) l = lm4;
            if (t >= 5 && par[t - 5] == t && lm5 > l) l = lm5;
            if (t >= 6 && par[t - 6] == t && lm6 > l) l = lm6;
            if (t >= 7 && par[t - 7] == t && lm7 > l) l = lm7;
            if (t >= 8 && par[t - 8] == t && lm8 > l) l = lm8;
            ++l;
            lvl[t] = l;
            cnt[l]++;
            if (l > maxl) maxl = l;
            lm8 = lm7; lm7 = lm6; lm6 = lm5; lm5 = lm4;
            lm4 = lm3; lm3 = lm2; lm2 = lm1; lm1 = l;
        }
        int run = 0;
        for (int l = 0; l <= maxl; ++l) {
            const int c = cnt[l];
            cnt[l] = run;
            off[l] = run;
            run += c;
        }
        off[maxl + 1] = run;       // == NN
        *nlv_g = maxl + 1;
        for (int t = 0; t < NN; ++t)
            order[cnt[lvl[t]]++] = t;   // stable: ascending node id per level
    }
    __syncthreads();
    for (int i = tid; i < NN; i += TPB) lvl_out[i] = lvl[i];
}

// ---------------------------------------------------------------- gx GEMM
// gx[n][m] = sum_d emb[inputs[n]][d] * Wx[m][d] + bx[m]   (m = g*1024+h)
// Stored as bf16 bits (16 MB workspace); error ~1e-4 << 3.8e-3 threshold.
__global__ void __launch_bounds__(256) gx_gemm(
    const int* __restrict__ idx, const float* __restrict__ emb,
    const float* __restrict__ Wx, const float* __restrict__ bx,
    unsigned short* __restrict__ gx)
{
    __shared__ float As[16][64];
    __shared__ float Bs[16][64];
    const int tid = threadIdx.x;
    const int tx = tid & 15, ty = tid >> 4;
    const int mt = blockIdx.x, nt = blockIdx.y;
    const int lrow = tid >> 2;            // 0..63
    const int lk   = (tid & 3) << 2;      // 0,4,8,12
    const int gn = nt * 64 + lrow;
    const int gm = mt * 64 + lrow;
    const float* arow = emb + (size_t)idx[gn] * HH;
    const float* wrow = Wx + (size_t)gm * HH;
    float acc[4][4] = {};
    for (int k0 = 0; k0 < HH; k0 += 16) {
        float4 av = *(const float4*)(arow + k0 + lk);
        float4 wv = *(const float4*)(wrow + k0 + lk);
        __syncthreads();
        As[lk + 0][lrow] = av.x; As[lk + 1][lrow] = av.y;
        As[lk + 2][lrow] = av.z; As[lk + 3][lrow] = av.w;
        Bs[lk + 0][lrow] = wv.x; Bs[lk + 1][lrow] = wv.y;
        Bs[lk + 2][lrow] = wv.z; Bs[lk + 3][lrow] = wv.w;
        __syncthreads();
        #pragma unroll
        for (int k = 0; k < 16; ++k) {
            const float4 a = *(const float4*)&As[k][ty * 4];
            const float4 b = *(const float4*)&Bs[k][tx * 4];
            const float aa[4] = {a.x, a.y, a.z, a.w};
            const float bb[4] = {b.x, b.y, b.z, b.w};
            #pragma unroll
            for (int i = 0; i < 4; ++i)
                #pragma unroll
                for (int j = 0; j < 4; ++j)
                    acc[i][j] += aa[i] * bb[j];
        }
    }
    #pragma unroll
    for (int i = 0; i < 4; ++i) {
        const int gr = nt * 64 + ty * 4 + i;
        #pragma unroll
        for (int j = 0; j < 4; ++j) {
            const int gc = mt * 64 + tx * 4 + j;
            gx[(size_t)gr * MM + gc] = (unsigned short)f2bf_bits(acc[i][j] + bx[gc]);
        }
    }
}

// ---------------------------------------------------------------- tree scan
// Level schedule with SPLIT-PHASE waits. Gate pre-activations are linear in
// child h, so children at level <= r-2 ("old") are processed with NO flag
// wait (previous level's acquire already covers them); only level r-1
// ("fresh", the defining children, ~1.5/node) sit behind the tight
// rendezvous. Old-child fetch+dots overlap the cross-XCD flag propagation.
// c state: 64 KB of dynamic LDS (c_all[NN][8]) owned by the WG.
__global__ void __launch_bounds__(TPB, 1) lstm_scan(
    const int* __restrict__ parent_g,
    const float* __restrict__ Wh,
    const float* __restrict__ bh,
    const unsigned short* __restrict__ gx,   // bf16 bits [N][4][H]
    const int* __restrict__ order_g,
    const int* __restrict__ off_g,
    const int* __restrict__ nlv_g,
    const int* __restrict__ lvl_g,
    int* flags,
    float* out)   // fp32: [ hs (NN*HH) | c_root (HH) | h_root (HH) ]
{
    // dynamic LDS: c_all[NN][8] (64 KB) + stage[MAXC][HH] (48 KB)
    extern __shared__ float dynlds[];
    float* c_all = dynlds;                                  // [NN*8]
    float (*stage)[HH] = (float (*)[HH])(dynlds + NN * 8);  // [MAXC][HH]

    const int b      = blockIdx.x;
    const int tid    = threadIdx.x;
    const int e_loc  = tid >> 5;       // 0..7
    const int lane32 = tid & 31;

    __shared__ int   par[NN];              // 8 KB
    __shared__ int   lvl_s[NN];            // 8 KB
    __shared__ int   order_s[NN];          // 8 KB
    __shared__ int   off_s[NN + 1];        // 8 KB
    __shared__ float gx_st[MAXNB][4][8];   // 1.5 KB
    __shared__ float dpart[MAXNB][4][8];   // 1.5 KB (i,o,u dots + fc)
    __shared__ float bh_s[4][8];           // 128 B
    __shared__ int   bt_node[MAXNB];
    __shared__ int   bt_oj[MAXC], bt_on[MAXC];
    __shared__ int   bt_fj[MAXC], bt_fn[MAXC];
    __shared__ int   bt_meta[4];           // nb, nold, nfresh, idx_end

    for (int i = tid; i < NN; i += TPB) par[i] = parent_g[i];
    for (int i = tid; i < NN; i += TPB) lvl_s[i] = lvl_g[i];
    for (int i = tid; i < NN; i += TPB) order_s[i] = order_g[i];
    const int nlv = *nlv_g;
    for (int i = tid; i <= nlv; i += TPB) off_s[i] = off_g[i];
    if (tid < 32)
        bh_s[tid >> 3][tid & 7] = bh[(size_t)(tid >> 3) * HH + b * 8 + (tid & 7)];

    float w_i[32], w_o[32], w_u[32], w_f[32];
    {
        const int e_glob = b * 8 + e_loc;
        const float* wi = Wh + ((size_t)(0 * HH + e_glob)) * HH + lane32;
        const float* wo = Wh + ((size_t)(1 * HH + e_glob)) * HH + lane32;
        const float* wu = Wh + ((size_t)(2 * HH + e_glob)) * HH + lane32;
        const float* wf = Wh + ((size_t)(3 * HH + e_glob)) * HH + lane32;
        #pragma unroll
        for (int s = 0; s < 32; ++s) {
            w_i[s] = wi[s * 32];
            w_o[s] = wo[s * 32];
            w_u[s] = wu[s * 32];
            w_f[s] = wf[s * 32];
        }
    }
    const float bhf = bh[3 * HH + b * 8 + e_loc];
    __syncthreads();

    int seen = -1;   // cached monotone lower bound of flags[tid] (tid < NWG)

    // ---- round 0: all leaves, elementwise-parallel, no cross-WG data
    {
        const int n0 = off_s[1];
        for (int base = 0; base < n0; base += 32) {
            const int i = base + (tid >> 3);
            if (i < n0) {
                const int t = order_s[i];
                const int e = tid & 7;
                const size_t g0 = (size_t)t * MM + b * 8 + e;
                const float iv = sigmoidf_(bf_bits2f(gx[g0]) + bh_s[0][e]);
                const float ov = sigmoidf_(bf_bits2f(gx[g0 + HH]) + bh_s[1][e]);
                const float uv = tanhf(bf_bits2f(gx[g0 + 2 * HH]) + bh_s[2][e]);
                const float c  = iv * uv;
                const float h  = ov * tanhf(c);
                c_all[t * 8 + e] = c;
                __hip_atomic_store(out + (size_t)t * HH + b * 8 + e, h,
                                   __ATOMIC_RELAXED, __HIP_MEMORY_SCOPE_AGENT);
            }
        }
        __syncthreads();   // drains vmcnt -> stores globally visible
        if (tid == 0)
            __hip_atomic_store(&flags[b], 0, __ATOMIC_RELEASE,
                               __HIP_MEMORY_SCOPE_AGENT);
    }

    // ---- rounds 1..nlv-1
    for (int r = 1; r < nlv; ++r) {
        const int rend = off_s[r + 1];
        int idx = off_s[r];
        while (idx < rend) {
            // batch build (tid0, serial over <=12 nodes; ~100 LDS reads)
            if (tid == 0) {
                int ie = idx, no = 0, nf = 0, nbn = 0;
                while (ie < rend && nbn < MAXNB) {
                    const int t  = order_s[ie];
                    const int lo = t >= 8 ? t - 8 : 0;
                    int k = 0;
                    for (int j = lo; j < t; ++j) k += (par[j] == t);
                    if (no + nf + k > MAXC) break;
                    for (int j = lo; j < t; ++j) {
                        if (par[j] != t) continue;
                        if (lvl_s[j] == r - 1) { bt_fj[nf] = j; bt_fn[nf] = nbn; ++nf; }
                        else                   { bt_oj[no] = j; bt_on[no] = nbn; ++no; }
                    }
                    bt_node[nbn++] = t;
                    ++ie;
                }
                bt_meta[0] = nbn; bt_meta[1] = no; bt_meta[2] = nf; bt_meta[3] = ie;
            }
            __syncthreads();
            const int nb = bt_meta[0], nold = bt_meta[1];
            const int nfr = bt_meta[2], idx_end = bt_meta[3];

            // ---- phase A: NO WAIT. Stage old-child rows (levels <= r-2,
            // visibility guaranteed by previous level's acquire) + gx + zero
            // partials. This latency overlaps other WGs' flag propagation.
            for (int w = tid; w < nold * HH; w += TPB) {
                const int sl = w >> 10, k = w & (HH - 1);
                stage[sl][k] = __hip_atomic_load(
                    out + (size_t)bt_oj[sl] * HH + k,
                    __ATOMIC_RELAXED, __HIP_MEMORY_SCOPE_AGENT);
            }
            for (int w = tid; w < nb * 32; w += TPB) {
                const int n = w >> 5, g = (w >> 3) & 3, e = w & 7;
                gx_st[n][g][e] =
                    bf_bits2f(gx[(size_t)bt_node[n] * MM + g * HH + b * 8 + e]);
                dpart[n][g][e] = 0.0f;
            }
            __syncthreads();

            // old-child dots (linear contributions, accumulated per node)
            for (int s = 0; s < nold; ++s) {
                const int n = bt_on[s];
                float d0 = 0.0f, d1 = 0.0f, d2 = 0.0f, d3 = 0.0f;
                #pragma unroll
                for (int q = 0; q < 32; ++q) {
                    const float hv = stage[s][lane32 + 32 * q];
                    d0 += w_i[q] * hv; d1 += w_o[q] * hv;
                    d2 += w_u[q] * hv; d3 += w_f[q] * hv;
                }
                #pragma unroll
                for (int o2 = 16; o2 > 0; o2 >>= 1) {
                    d0 += __shfl_down(d0, o2, 32); d1 += __shfl_down(d1, o2, 32);
                    d2 += __shfl_down(d2, o2, 32); d3 += __shfl_down(d3, o2, 32);
                }
                if (lane32 == 0) {
                    dpart[n][0][e_loc] += d0;
                    dpart[n][1][e_loc] += d1;
                    dpart[n][2][e_loc] += d2;
                    dpart[n][3][e_loc] +=
                        sigmoidf_(gx_st[n][3][e_loc] + d3 + bhf)
                        * c_all[bt_oj[s] * 8 + e_loc];
                }
            }

            // ---- phase B: tight wait for level r-1 publications
            if (tid < NWG && seen < r - 1) {
                int v;
                while ((v = __hip_atomic_load(&flags[tid], __ATOMIC_ACQUIRE,
                                              __HIP_MEMORY_SCOPE_AGENT)) < r - 1)
                    __builtin_amdgcn_s_sleep(1);
                seen = v;
            }
            __syncthreads();

            for (int w = tid; w < nfr * HH; w += TPB) {
                const int sl = w >> 10, k = w & (HH - 1);
                stage[sl][k] = __hip_atomic_load(
                    out + (size_t)bt_fj[sl] * HH + k,
                    __ATOMIC_RELAXED, __HIP_MEMORY_SCOPE_AGENT);
            }
            __syncthreads();

            // fresh-child dots
            for (int s = 0; s < nfr; ++s) {
                const int n = bt_fn[s];
                float d0 = 0.0f, d1 = 0.0f, d2 = 0.0f, d3 = 0.0f;
                #pragma unroll
                for (int q = 0; q < 32; ++q) {
                    const float hv = stage[s][lane32 + 32 * q];
                    d0 += w_i[q] * hv; d1 += w_o[q] * hv;
                    d2 += w_u[q] * hv; d3 += w_f[q] * hv;
                }
                #pragma unroll
                for (int o2 = 16; o2 > 0; o2 >>= 1) {
                    d0 += __shfl_down(d0, o2, 32); d1 += __shfl_down(d1, o2, 32);
                    d2 += __shfl_down(d2, o2, 32); d3 += __shfl_down(d3, o2, 32);
                }
                if (lane32 == 0) {
                    dpart[n][0][e_loc] += d0;
                    dpart[n][1][e_loc] += d1;
                    dpart[n][2][e_loc] += d2;
                    dpart[n][3][e_loc] +=
                        sigmoidf_(gx_st[n][3][e_loc] + d3 + bhf)
                        * c_all[bt_fj[s] * 8 + e_loc];
                }
            }
            __syncthreads();   // dpart complete before gate threads read it

            // gates: one thread per (node, elem)
            if (tid < nb * 8) {
                const int n = tid >> 3, e = tid & 7;
                const int t = bt_node[n];
                const float iv = sigmoidf_(gx_st[n][0][e] + dpart[n][0][e] + bh_s[0][e]);
                const float ov = sigmoidf_(gx_st[n][1][e] + dpart[n][1][e] + bh_s[1][e]);
                const float uv = tanhf    (gx_st[n][2][e] + dpart[n][2][e] + bh_s[2][e]);
                const float c  = iv * uv + dpart[n][3][e];
                const float h  = ov * tanhf(c);
                c_all[t * 8 + e] = c;
                __hip_atomic_store(out + (size_t)t * HH + b * 8 + e, h,
                                   __ATOMIC_RELAXED, __HIP_MEMORY_SCOPE_AGENT);
                if (t == NN - 1) {
                    __hip_atomic_store(out + (size_t)NN * HH + b * 8 + e, c,
                                       __ATOMIC_RELAXED, __HIP_MEMORY_SCOPE_AGENT);
                    __hip_atomic_store(out + (size_t)NN * HH + HH + b * 8 + e, h,
                                       __ATOMIC_RELAXED, __HIP_MEMORY_SCOPE_AGENT);
                }
            }
            __syncthreads();   // reuse guard + drains h stores (vmcnt)
            idx = idx_end;
        }
        if (tid == 0)
            __hip_atomic_store(&flags[b], r, __ATOMIC_RELEASE,
                               __HIP_MEMORY_SCOPE_AGENT);
    }
}

// ---------------------------------------------------------------- launch
extern "C" void kernel_launch(void* const* d_in, const int* in_sizes, int n_in,
                              void* d_out, int out_size, void* d_ws, size_t ws_size,
                              hipStream_t stream)
{
    const int*   inputs = (const int*)d_in[0];
    const int*   parent = (const int*)d_in[1];
    const float* emb    = (const float*)d_in[2];
    const float* Wx     = (const float*)d_in[3];
    const float* bx     = (const float*)d_in[4];
    const float* Wh     = (const float*)d_in[5];
    const float* bh     = (const float*)d_in[6];
    float* out = (float*)d_out;          // fp32 output (reference is fp32)

    char* ws = (char*)d_ws;
    int*  flags = (int*)ws;                                     // 512 B
    unsigned short* gx = (unsigned short*)(ws + 1024);          // 16 MB bf16
    char* ws2 = ws + 1024 + (size_t)NN * MM * 2;
    int*  order = (int*)ws2;                                    // 8 KB
    int*  off   = (int*)(ws2 + 8192);                           // 8.2 KB
    int*  nlv   = (int*)(ws2 + 8192 + 8448);                    // 4 B
    int*  lvl   = (int*)(ws2 + 8192 + 8448 + 64);               // 8 KB

    // dynamic LDS: c_all (64 KB) + stage (48 KB) = 112 KB; static ~36 KB
    const int dyn_lds = (NN * 8 + MAXC * HH) * (int)sizeof(float);
    hipFuncSetAttribute(reinterpret_cast<const void*>(lstm_scan),
                        hipFuncAttributeMaxDynamicSharedMemorySize, dyn_lds);

    hipLaunchKernelGGL(init_flags, dim3(1), dim3(128), 0, stream, flags);
    hipLaunchKernelGGL(build_sched, dim3(1), dim3(TPB), 0, stream,
                       parent, order, off, nlv, lvl);
    hipLaunchKernelGGL(gx_gemm, dim3(MM / 64, NN / 64), dim3(256), 0, stream,
                       inputs, emb, Wx, bx, gx);
    hipLaunchKernelGGL(lstm_scan, dim3(NWG), dim3(TPB), dyn_lds, stream,
                       parent, Wh, bh, gx, order, off, nlv, lvl, flags, out);
}